// Round 1
// baseline (76.101 us; speedup 1.0000x reference)
//
#include <hip/hip_runtime.h>
#include <hip/hip_bf16.h>

#define S_LEN 127
#define NB    32
#define HDIM  256
#define DH    64
#define SCALE_F 0.125f
#define NEG_F  -100000.0f

typedef __bf16 bf16x8 __attribute__((ext_vector_type(8)));
typedef float  f32x4  __attribute__((ext_vector_type(4)));

// ---------------------------------------------------------------------------
// Wave-level bf16 MFMA GEMM: out[M,256] = A[M,256] @ W[256,256]^T + bias
// One 64-thread wave computes a 32x32 output tile. K = 256 (8 MFMA k-steps).
// A and W are f32, converted to bf16 on the fly (threshold 0.132 permits).
// Fragment layout (verified m89): A/B lane l holds 8 contiguous-K elems at
// row/col (l&15), kbase ((l>>4)*8); C/D: col = lane&15, row = (lane>>4)*4+reg.
// ---------------------------------------------------------------------------
__global__ __launch_bounds__(64) void gemm_bias_256(
    const float* __restrict__ A, const float* __restrict__ W,
    const float* __restrict__ bias, float* __restrict__ out)
{
  const int lane = threadIdx.x & 63;
  const int r  = lane & 15;
  const int ks = (lane >> 4) << 3;
  const long row0 = (long)blockIdx.x * 32;
  const long col0 = (long)blockIdx.y * 32;
  f32x4 acc[2][2] = {};
  const float* Ab = A + row0 * HDIM + ks;
  const float* Wb = W + col0 * HDIM + ks;
#pragma unroll
  for (int kb = 0; kb < 256; kb += 32) {
    bf16x8 af[2], bf[2];
#pragma unroll
    for (int mi = 0; mi < 2; ++mi) {
      const float* pa = Ab + (mi * 16 + r) * HDIM + kb;
      const float* pw = Wb + (mi * 16 + r) * HDIM + kb;
#pragma unroll
      for (int j = 0; j < 8; ++j) {
        af[mi][j] = (__bf16)pa[j];
        bf[mi][j] = (__bf16)pw[j];
      }
    }
#pragma unroll
    for (int mi = 0; mi < 2; ++mi)
#pragma unroll
      for (int ni = 0; ni < 2; ++ni)
        acc[mi][ni] = __builtin_amdgcn_mfma_f32_16x16x32_bf16(
            af[mi], bf[ni], acc[mi][ni], 0, 0, 0);
  }
  const int crow = (lane >> 4) * 4;
  const int ccol = lane & 15;
#pragma unroll
  for (int mi = 0; mi < 2; ++mi)
#pragma unroll
    for (int ni = 0; ni < 2; ++ni) {
      const int oc = (int)col0 + ni * 16 + ccol;
      const float bv = bias[oc];
#pragma unroll
      for (int rg = 0; rg < 4; ++rg)
        out[(row0 + mi * 16 + crow + rg) * HDIM + oc] = acc[mi][ni][rg] + bv;
    }
}

// ---------------------------------------------------------------------------
// Fused sparse attention. One 256-thread block per (q, b).
// score[h,k] = sum_d (q[h,d]+eq[k,q,d]) * (k[k,h,d]+ek[q,k,d])  (f32 VALU)
// Mask sparsity: for q>=3 only k in {0,1,2,blk,blk+1} survive keep-mask;
// graph!=0 filters further. exp(-1e5 - max) == 0 exactly in f32, so masked
// columns are skipped exactly. All-masked row -> uniform 1/127 (exact).
// ---------------------------------------------------------------------------
__global__ __launch_bounds__(256) void attn_kernel(
    const float* __restrict__ qp, const float* __restrict__ kp,
    const float* __restrict__ vp, const int* __restrict__ graph,
    const float* __restrict__ ekt, const float* __restrict__ evt,
    const float* __restrict__ eqt, float* __restrict__ xp)
{
  const int q = blockIdx.x;   // 0..126
  const int b = blockIdx.y;   // 0..31
  const int t = threadIdx.x;  // 0..255
  const int w = t >> 6;       // wave id 0..3
  const int l = t & 63;       // lane

  __shared__ int   s_list[S_LEN];
  __shared__ float s_attn[4][S_LEN];
  __shared__ int   s_cnt[2];

  // ---- build compacted valid-k list (waves 0,1; deterministic via ballot) ----
  bool valid = false;
  const int k0 = w * 64 + l;
  if (w < 2 && k0 < S_LEN) {
    const int g = graph[((size_t)b * S_LEN + q) * S_LEN + k0];
    bool keep;
    if (q < 3 || k0 < 3) keep = true;
    else {
      const int blk = 3 + 2 * ((q - 3) >> 1);
      keep = (k0 >= blk) & (k0 < blk + 2);
    }
    valid = (g != 0) && keep;
  }
  const unsigned long long bal = __ballot(valid);
  if (w < 2 && l == 0) s_cnt[w] = (int)__popcll(bal);
  __syncthreads();
  int n = s_cnt[0] + s_cnt[1];
  if (valid) {
    const int pos = (int)__popcll(bal & ((1ull << l) - 1ull)) + (w ? s_cnt[0] : 0);
    s_list[pos] = k0;
  }
  __syncthreads();

  if (n == 0) {
    // all columns masked: softmax of uniform -1e5 -> exactly 1/127 everywhere
    if (t < S_LEN) {
      s_list[t] = t;
      const float u = 1.0f / 127.0f;
      s_attn[0][t] = u; s_attn[1][t] = u; s_attn[2][t] = u; s_attn[3][t] = u;
    }
    n = S_LEN;
  } else {
    // ---- scores: one valid column per wave per iteration, 64-lane dot ----
    const float* qrow = qp + ((size_t)b * S_LEN + q) * HDIM;
    const float  q0 = qrow[l], q1 = qrow[64 + l], q2 = qrow[128 + l], q3 = qrow[192 + l];
    const float* eqb = eqt + ((size_t)b * S_LEN * S_LEN + q) * DH;      // + k*S*DH + d
    const float* ekb = ekt + ((size_t)(b * S_LEN + q)) * S_LEN * DH;    // + k*DH + d

    for (int i0 = 0; i0 < n; i0 += 4) {
      const int i = i0 + w;
      float p0 = 0.f, p1 = 0.f, p2 = 0.f, p3 = 0.f;
      if (i < n) {
        const int kk = s_list[i];
        const float eqv = eqb[(size_t)kk * (S_LEN * DH) + l];
        const float ekv = ekb[kk * DH + l];
        const float* krow = kp + ((size_t)b * S_LEN + kk) * HDIM;
        p0 = (q0 + eqv) * (krow[l] + ekv);
        p1 = (q1 + eqv) * (krow[64 + l] + ekv);
        p2 = (q2 + eqv) * (krow[128 + l] + ekv);
        p3 = (q3 + eqv) * (krow[192 + l] + ekv);
      }
#pragma unroll
      for (int off = 32; off; off >>= 1) {
        p0 += __shfl_xor(p0, off, 64);
        p1 += __shfl_xor(p1, off, 64);
        p2 += __shfl_xor(p2, off, 64);
        p3 += __shfl_xor(p3, off, 64);
      }
      if (i < n && l < 4) {
        const float s = (l == 0) ? p0 : (l == 1) ? p1 : (l == 2) ? p2 : p3;
        s_attn[l][i] = s * SCALE_F;
      }
    }
    __syncthreads();

    // ---- softmax per head: wave w handles head w over n compacted scores ----
    {
      const float v0 = (l < n) ? s_attn[w][l] : -INFINITY;
      const float v1 = (64 + l < n) ? s_attn[w][64 + l] : -INFINITY;
      float mx = fmaxf(v0, v1);
#pragma unroll
      for (int off = 32; off; off >>= 1) mx = fmaxf(mx, __shfl_xor(mx, off, 64));
      const float e0 = (l < n) ? expf(v0 - mx) : 0.f;
      const float e1 = (64 + l < n) ? expf(v1 - mx) : 0.f;
      float sm = e0 + e1;
#pragma unroll
      for (int off = 32; off; off >>= 1) sm += __shfl_xor(sm, off, 64);
      const float inv = 1.0f / sm;
      if (l < n) s_attn[w][l] = e0 * inv;
      if (64 + l < n) s_attn[w][64 + l] = e1 * inv;
    }
  }
  __syncthreads();

  // ---- output: x[h=w, d=l] = sum over valid k of attn * (v[k,h,d] + ev[q,k,d]) ----
  {
    const float* evb = evt + ((size_t)(b * S_LEN + q)) * S_LEN * DH;
    const float* vb  = vp + (size_t)b * S_LEN * HDIM + w * DH;
    float acc = 0.f;
    for (int i = 0; i < n; ++i) {
      const int kk = s_list[i];
      const float a = s_attn[w][i];
      acc += a * (vb[(size_t)kk * HDIM + l] + evb[kk * DH + l]);
    }
    xp[((size_t)b * S_LEN + q) * HDIM + t] = acc;
  }
}

extern "C" void kernel_launch(void* const* d_in, const int* in_sizes, int n_in,
                              void* d_out, int out_size, void* d_ws, size_t ws_size,
                              hipStream_t stream) {
  const float* query = (const float*)d_in[0];
  const float* key   = (const float*)d_in[1];
  const float* value = (const float*)d_in[2];
  const int*   graph = (const int*)d_in[3];
  const float* ekt   = (const float*)d_in[4];  // edge_key   [B,S,S,D]
  const float* evt   = (const float*)d_in[5];  // edge_value [B,S,S,D]
  const float* eqt   = (const float*)d_in[6];  // edge_query [B,S,S,D]
  const float* Wq = (const float*)d_in[7];  const float* bq = (const float*)d_in[8];
  const float* Wk = (const float*)d_in[9];  const float* bk = (const float*)d_in[10];
  const float* Wv = (const float*)d_in[11]; const float* bv = (const float*)d_in[12];
  const float* Wo = (const float*)d_in[13]; const float* bo = (const float*)d_in[14];
  float* out = (float*)d_out;

  const size_t NTOK = (size_t)NB * S_LEN;        // 4064 rows
  float* qp = (float*)d_ws;
  float* kp = qp + NTOK * HDIM;
  float* vp = kp + NTOK * HDIM;
  float* xp = vp + NTOK * HDIM;

  dim3 gg(127, 8);  // 4064/32 row tiles x 256/32 col tiles
  gemm_bias_256<<<gg, 64, 0, stream>>>(query, Wq, bq, qp);
  gemm_bias_256<<<gg, 64, 0, stream>>>(key,   Wk, bk, kp);
  gemm_bias_256<<<gg, 64, 0, stream>>>(value, Wv, bv, vp);

  attn_kernel<<<dim3(S_LEN, NB), 256, 0, stream>>>(qp, kp, vp, graph, ekt, evt, eqt, xp);

  gemm_bias_256<<<gg, 64, 0, stream>>>(xp, Wo, bo, out);
}